// Round 1
// baseline (96.454 us; speedup 1.0000x reference)
//
#include <hip/hip_runtime.h>

#define NEG_SLOPE 0.2f

__device__ __forceinline__ void atomicMaxF(float* addr, float v) {
    if (v >= 0.f) {
        atomicMax((int*)addr, __float_as_int(v));
    } else {
        atomicMin((unsigned int*)addr, __float_as_uint(v));
    }
}

// K0: tiny precompute of folded vectors.
// wave f<384:   vs[f]=W_lin[f,:]·W_out, va[f]=W_lin[f,:]·att_src, vb[f]=W_lin[f,:]·att_dst
// wave 384+d (d<16): we[d]=W_edge[d,:]·att_edge
// wave 400:     cb = bias_conv·W_out + b_out
__global__ void k0_precompute(const float* __restrict__ Wlin,
                              const float* __restrict__ att_src,
                              const float* __restrict__ att_dst,
                              const float* __restrict__ Wedge,
                              const float* __restrict__ att_edge,
                              const float* __restrict__ bias_conv,
                              const float* __restrict__ Wout,
                              const float* __restrict__ bout,
                              float* __restrict__ vs, float* __restrict__ va,
                              float* __restrict__ vb, float* __restrict__ we,
                              float* __restrict__ cb) {
    int wid  = (blockIdx.x * blockDim.x + threadIdx.x) >> 6;
    int lane = threadIdx.x & 63;
    if (wid < 384) {
        int f = wid;
        float a = 0.f, b = 0.f, c = 0.f;
        for (int k = lane; k < 384; k += 64) {
            float w = Wlin[f * 384 + k];
            a += w * Wout[k];
            b += w * att_src[k];
            c += w * att_dst[k];
        }
        for (int off = 32; off > 0; off >>= 1) {
            a += __shfl_down(a, off);
            b += __shfl_down(b, off);
            c += __shfl_down(c, off);
        }
        if (lane == 0) { vs[f] = a; va[f] = b; vb[f] = c; }
    } else if (wid < 400) {
        int d = wid - 384;
        float a = 0.f;
        for (int k = lane; k < 384; k += 64) a += Wedge[d * 384 + k] * att_edge[k];
        for (int off = 32; off > 0; off >>= 1) a += __shfl_down(a, off);
        if (lane == 0) we[d] = a;
    } else if (wid == 400) {
        float a = 0.f;
        for (int k = lane; k < 384; k += 64) a += bias_conv[k] * Wout[k];
        for (int off = 32; off > 0; off >>= 1) a += __shfl_down(a, off);
        if (lane == 0) cb[0] = a + bout[0];
    }
}

// K1: one wave per node. s/asrc/adst dot products over the 384-wide row of x.
// Also zero-initializes the accumulator arrays (deg, aesum, denom, num).
__global__ void k1_node(const float* __restrict__ x,
                        const float* __restrict__ vs, const float* __restrict__ va,
                        const float* __restrict__ vb,
                        float* __restrict__ s, float* __restrict__ asrc,
                        float* __restrict__ adst, float* __restrict__ deg,
                        float* __restrict__ aesum, float* __restrict__ denom,
                        float* __restrict__ num, int n_nodes) {
    int wid  = (blockIdx.x * blockDim.x + threadIdx.x) >> 6;
    int lane = threadIdx.x & 63;
    if (wid >= n_nodes) return;
    const float2* xr  = (const float2*)(x + (size_t)wid * 384);
    const float2* vs2 = (const float2*)vs;
    const float2* va2 = (const float2*)va;
    const float2* vb2 = (const float2*)vb;
    float a = 0.f, b = 0.f, c = 0.f;
#pragma unroll
    for (int k = 0; k < 3; ++k) {
        int idx = lane + 64 * k;
        float2 xv = xr[idx];
        float2 w1 = vs2[idx];
        float2 w2 = va2[idx];
        float2 w3 = vb2[idx];
        a += xv.x * w1.x + xv.y * w1.y;
        b += xv.x * w2.x + xv.y * w2.y;
        c += xv.x * w3.x + xv.y * w3.y;
    }
    for (int off = 32; off > 0; off >>= 1) {
        a += __shfl_down(a, off);
        b += __shfl_down(b, off);
        c += __shfl_down(c, off);
    }
    if (lane == 0) {
        s[wid] = a; asrc[wid] = b; adst[wid] = c;
        deg[wid] = 0.f; aesum[wid] = 0.f; denom[wid] = 0.f; num[wid] = 0.f;
    }
}

// K2: one thread per edge: ae_raw[e] = edge_attr[e,:]·we; accumulate per-dst sums.
__global__ void k2_edge(const float* __restrict__ ea, const int* __restrict__ dst,
                        const float* __restrict__ we, float* __restrict__ ae_raw,
                        float* __restrict__ deg, float* __restrict__ aesum, int n_edges) {
    int e = blockIdx.x * blockDim.x + threadIdx.x;
    if (e >= n_edges) return;
    const float4* r  = (const float4*)(ea + (size_t)e * 16);
    const float4* w4 = (const float4*)we;
    float a = 0.f;
#pragma unroll
    for (int j = 0; j < 4; ++j) {
        float4 v = r[j], w = w4[j];
        a += v.x * w.x + v.y * w.y + v.z * w.z + v.w * w.w;
    }
    ae_raw[e] = a;
    int d = dst[e];
    atomicAdd(&aesum[d], a);
    atomicAdd(&deg[d], 1.0f);
}

// K3: per-node self-loop logit; initializes the running max with it.
__global__ void k3_node(const float* __restrict__ asrc, const float* __restrict__ adst,
                        const float* __restrict__ deg, const float* __restrict__ aesum,
                        float* __restrict__ aloop, float* __restrict__ amax, int n_nodes) {
    int n = blockIdx.x * blockDim.x + threadIdx.x;
    if (n >= n_nodes) return;
    float d = deg[n];
    d = d < 1.f ? 1.f : d;
    float al = asrc[n] + adst[n] + aesum[n] / d;
    al = al >= 0.f ? al : NEG_SLOPE * al;
    aloop[n] = al;
    amax[n]  = al;
}

// K4: per-edge logit + segment max via float atomicMax.
__global__ void k4_edge(const int* __restrict__ src, const int* __restrict__ dst,
                        const float* __restrict__ ae_raw, const float* __restrict__ asrc,
                        const float* __restrict__ adst, float* __restrict__ alpha_e,
                        float* __restrict__ amax, int n_edges) {
    int e = blockIdx.x * blockDim.x + threadIdx.x;
    if (e >= n_edges) return;
    float al = asrc[src[e]] + adst[dst[e]] + ae_raw[e];
    al = al >= 0.f ? al : NEG_SLOPE * al;
    alpha_e[e] = al;
    atomicMaxF(&amax[dst[e]], al);
}

// K5: exp + segment sums (numerator carries the folded source scalar s[src]).
// Covers N self loops then E edges in one grid.
__global__ void k5_expsum(const int* __restrict__ src, const int* __restrict__ dst,
                          const float* __restrict__ alpha_e, const float* __restrict__ aloop,
                          const float* __restrict__ amax, const float* __restrict__ s,
                          float* __restrict__ denom, float* __restrict__ num,
                          int n_nodes, int n_edges) {
    int i = blockIdx.x * blockDim.x + threadIdx.x;
    if (i < n_nodes) {
        float ex = expf(aloop[i] - amax[i]);
        atomicAdd(&denom[i], ex);
        atomicAdd(&num[i], ex * s[i]);
    } else {
        int e = i - n_nodes;
        if (e < n_edges) {
            int d = dst[e];
            float ex = expf(alpha_e[e] - amax[d]);
            atomicAdd(&denom[d], ex);
            atomicAdd(&num[d], ex * s[src[e]]);
        }
    }
}

// K6: final output: relu(num/denom + cb)
__global__ void k6_out(const float* __restrict__ denom, const float* __restrict__ num,
                       const float* __restrict__ cb, float* __restrict__ out, int n_nodes) {
    int n = blockIdx.x * blockDim.x + threadIdx.x;
    if (n >= n_nodes) return;
    float v = num[n] / denom[n] + cb[0];
    out[n] = v > 0.f ? v : 0.f;
}

extern "C" void kernel_launch(void* const* d_in, const int* in_sizes, int n_in,
                              void* d_out, int out_size, void* d_ws, size_t ws_size,
                              hipStream_t stream) {
    const float* x        = (const float*)d_in[0];
    const int*   eidx     = (const int*)d_in[1];
    const float* ea       = (const float*)d_in[2];
    const float* Wlin     = (const float*)d_in[3];
    const float* att_src  = (const float*)d_in[4];
    const float* att_dst  = (const float*)d_in[5];
    const float* Wedge    = (const float*)d_in[6];
    const float* att_edge = (const float*)d_in[7];
    const float* bias_c   = (const float*)d_in[8];
    const float* Wout     = (const float*)d_in[9];
    const float* bout     = (const float*)d_in[10];
    float*       out      = (float*)d_out;

    const int N = in_sizes[0] / 384;   // 50000
    const int E = in_sizes[2] / 16;    // 200000
    const int* src = eidx;
    const int* dst = eidx + E;

    float* W = (float*)d_ws;
    float* vs    = W;              // 384
    float* va    = W + 384;        // 384
    float* vb    = W + 768;        // 384
    float* we    = W + 1152;       // 16
    float* cb    = W + 1168;       // 1
    float* s     = W + 1280;       // N
    float* asrc  = s + N;
    float* adst  = asrc + N;
    float* deg   = adst + N;
    float* aesum = deg + N;
    float* aloop = aesum + N;
    float* amax  = aloop + N;
    float* denom = amax + N;
    float* num   = denom + N;
    float* ae_raw  = num + N;      // E
    float* alpha_e = ae_raw + E;   // E

    // K0: 401 waves
    {
        int waves = 401;
        int blocks = (waves * 64 + 255) / 256;
        k0_precompute<<<blocks, 256, 0, stream>>>(Wlin, att_src, att_dst, Wedge,
                                                  att_edge, bias_c, Wout, bout,
                                                  vs, va, vb, we, cb);
    }
    // K1: one wave per node
    {
        int blocks = (N * 64 + 255) / 256;
        k1_node<<<blocks, 256, 0, stream>>>(x, vs, va, vb, s, asrc, adst, deg,
                                            aesum, denom, num, N);
    }
    // K2: one thread per edge
    {
        int blocks = (E + 255) / 256;
        k2_edge<<<blocks, 256, 0, stream>>>(ea, dst, we, ae_raw, deg, aesum, E);
    }
    // K3
    {
        int blocks = (N + 255) / 256;
        k3_node<<<blocks, 256, 0, stream>>>(asrc, adst, deg, aesum, aloop, amax, N);
    }
    // K4
    {
        int blocks = (E + 255) / 256;
        k4_edge<<<blocks, 256, 0, stream>>>(src, dst, ae_raw, asrc, adst, alpha_e, amax, E);
    }
    // K5: N self loops + E edges
    {
        int blocks = (N + E + 255) / 256;
        k5_expsum<<<blocks, 256, 0, stream>>>(src, dst, alpha_e, aloop, amax, s,
                                              denom, num, N, E);
    }
    // K6
    {
        int blocks = (N + 255) / 256;
        k6_out<<<blocks, 256, 0, stream>>>(denom, num, cb, out, N);
    }
}

// Round 2
// 78.262 us; speedup vs baseline: 1.2325x; 1.2325x over previous
//
#include <hip/hip_runtime.h>

#define NEG_SLOPE 0.2f

// K0: tiny precompute of folded vectors (GAT output is linear in h, so fold
// W_lin through W_out / att_src / att_dst once).
// wave f<384:   vs[f]=W_lin[f,:]·W_out, va[f]=W_lin[f,:]·att_src, vb[f]=W_lin[f,:]·att_dst
// wave 384+d (d<16): we[d]=W_edge[d,:]·att_edge
// wave 400:     cb = bias_conv·W_out + b_out
__global__ void k0_precompute(const float* __restrict__ Wlin,
                              const float* __restrict__ att_src,
                              const float* __restrict__ att_dst,
                              const float* __restrict__ Wedge,
                              const float* __restrict__ att_edge,
                              const float* __restrict__ bias_conv,
                              const float* __restrict__ Wout,
                              const float* __restrict__ bout,
                              float* __restrict__ vs, float* __restrict__ va,
                              float* __restrict__ vb, float* __restrict__ we,
                              float* __restrict__ cb) {
    int wid  = (blockIdx.x * blockDim.x + threadIdx.x) >> 6;
    int lane = threadIdx.x & 63;
    if (wid < 384) {
        int f = wid;
        float a = 0.f, b = 0.f, c = 0.f;
        for (int k = lane; k < 384; k += 64) {
            float w = Wlin[f * 384 + k];
            a += w * Wout[k];
            b += w * att_src[k];
            c += w * att_dst[k];
        }
        for (int off = 32; off > 0; off >>= 1) {
            a += __shfl_down(a, off);
            b += __shfl_down(b, off);
            c += __shfl_down(c, off);
        }
        if (lane == 0) { vs[f] = a; va[f] = b; vb[f] = c; }
    } else if (wid < 400) {
        int d = wid - 384;
        float a = 0.f;
        for (int k = lane; k < 384; k += 64) a += Wedge[d * 384 + k] * att_edge[k];
        for (int off = 32; off > 0; off >>= 1) a += __shfl_down(a, off);
        if (lane == 0) we[d] = a;
    } else if (wid == 400) {
        float a = 0.f;
        for (int k = lane; k < 384; k += 64) a += bias_conv[k] * Wout[k];
        for (int off = 32; off > 0; off >>= 1) a += __shfl_down(a, off);
        if (lane == 0) cb[0] = a + bout[0];
    }
}

// K1: one wave per node: s/asrc/adst dot products over the 384-wide row of x.
// Lane 0 also zero-inits the per-node accumulators (same-stream ordering
// guarantees this completes before K2's atomics).
__global__ void k1_node(const float* __restrict__ x,
                        const float* __restrict__ vs, const float* __restrict__ va,
                        const float* __restrict__ vb,
                        float* __restrict__ s, float* __restrict__ asrc,
                        float* __restrict__ adst, float* __restrict__ deg,
                        float* __restrict__ aesum, float* __restrict__ denom,
                        float* __restrict__ num, int n_nodes) {
    int wid  = (blockIdx.x * blockDim.x + threadIdx.x) >> 6;
    int lane = threadIdx.x & 63;
    if (wid >= n_nodes) return;
    const float2* xr  = (const float2*)(x + (size_t)wid * 384);
    const float2* vs2 = (const float2*)vs;
    const float2* va2 = (const float2*)va;
    const float2* vb2 = (const float2*)vb;
    float a = 0.f, b = 0.f, c = 0.f;
#pragma unroll
    for (int k = 0; k < 3; ++k) {
        int idx = lane + 64 * k;
        float2 xv = xr[idx];
        float2 w1 = vs2[idx];
        float2 w2 = va2[idx];
        float2 w3 = vb2[idx];
        a += xv.x * w1.x + xv.y * w1.y;
        b += xv.x * w2.x + xv.y * w2.y;
        c += xv.x * w3.x + xv.y * w3.y;
    }
    for (int off = 32; off > 0; off >>= 1) {
        a += __shfl_down(a, off);
        b += __shfl_down(b, off);
        c += __shfl_down(c, off);
    }
    if (lane == 0) {
        s[wid] = a; asrc[wid] = b; adst[wid] = c;
        deg[wid] = 0.f; aesum[wid] = 0.f; denom[wid] = 0.f; num[wid] = 0.f;
    }
}

// K2: ALL per-edge work in one pass (no segment-max: logits are |.|<~25 so
// raw exp is fp32-safe and the softmax ratio is mathematically unchanged).
//   ae = edge_attr[e,:]·we
//   aesum[dst] += ae ; deg[dst] += 1           (self-loop mean inputs)
//   alpha = leaky_relu(asrc[src]+adst[dst]+ae)
//   ex = exp(alpha); denom[dst] += ex; num[dst] += ex * s[src]
__global__ void k2_edge(const float* __restrict__ ea, const int* __restrict__ src,
                        const int* __restrict__ dst, const float* __restrict__ we,
                        const float* __restrict__ asrc, const float* __restrict__ adst,
                        const float* __restrict__ s,
                        float* __restrict__ deg, float* __restrict__ aesum,
                        float* __restrict__ denom, float* __restrict__ num,
                        int n_edges) {
    int e = blockIdx.x * blockDim.x + threadIdx.x;
    if (e >= n_edges) return;
    const float4* r  = (const float4*)(ea + (size_t)e * 16);
    const float4* w4 = (const float4*)we;
    float a = 0.f;
#pragma unroll
    for (int j = 0; j < 4; ++j) {
        float4 v = r[j], w = w4[j];
        a += v.x * w.x + v.y * w.y + v.z * w.z + v.w * w.w;
    }
    int sn = src[e], dn = dst[e];
    atomicAdd(&aesum[dn], a);
    atomicAdd(&deg[dn], 1.0f);
    float al = asrc[sn] + adst[dn] + a;
    al = al >= 0.f ? al : NEG_SLOPE * al;
    float ex = __expf(al);
    atomicAdd(&denom[dn], ex);
    atomicAdd(&num[dn], ex * s[sn]);
}

// K3: fold in the self-loop term and produce the output:
//   al = leaky_relu(asrc+adst+aesum/max(deg,1)); ex = exp(al)
//   out = relu((num + ex*s)/(denom + ex) + cb)
__global__ void k3_out(const float* __restrict__ asrc, const float* __restrict__ adst,
                       const float* __restrict__ deg, const float* __restrict__ aesum,
                       const float* __restrict__ denom, const float* __restrict__ num,
                       const float* __restrict__ s, const float* __restrict__ cb,
                       float* __restrict__ out, int n_nodes) {
    int n = blockIdx.x * blockDim.x + threadIdx.x;
    if (n >= n_nodes) return;
    float d = deg[n];
    d = d < 1.f ? 1.f : d;
    float al = asrc[n] + adst[n] + aesum[n] / d;
    al = al >= 0.f ? al : NEG_SLOPE * al;
    float ex = __expf(al);
    float v = (num[n] + ex * s[n]) / (denom[n] + ex) + cb[0];
    out[n] = v > 0.f ? v : 0.f;
}

extern "C" void kernel_launch(void* const* d_in, const int* in_sizes, int n_in,
                              void* d_out, int out_size, void* d_ws, size_t ws_size,
                              hipStream_t stream) {
    const float* x        = (const float*)d_in[0];
    const int*   eidx     = (const int*)d_in[1];
    const float* ea       = (const float*)d_in[2];
    const float* Wlin     = (const float*)d_in[3];
    const float* att_src  = (const float*)d_in[4];
    const float* att_dst  = (const float*)d_in[5];
    const float* Wedge    = (const float*)d_in[6];
    const float* att_edge = (const float*)d_in[7];
    const float* bias_c   = (const float*)d_in[8];
    const float* Wout     = (const float*)d_in[9];
    const float* bout     = (const float*)d_in[10];
    float*       out      = (float*)d_out;

    const int N = in_sizes[0] / 384;   // 50000
    const int E = in_sizes[2] / 16;    // 200000
    const int* src = eidx;
    const int* dst = eidx + E;

    float* W = (float*)d_ws;
    float* vs    = W;              // 384
    float* va    = W + 384;        // 384
    float* vb    = W + 768;        // 384
    float* we    = W + 1152;       // 16
    float* cb    = W + 1168;       // 1
    float* s     = W + 1280;       // N each below
    float* asrc  = s + N;
    float* adst  = asrc + N;
    float* deg   = adst + N;
    float* aesum = deg + N;
    float* denom = aesum + N;
    float* num   = denom + N;

    // K0: 401 waves of weight folding
    k0_precompute<<<(401 * 64 + 255) / 256, 256, 0, stream>>>(
        Wlin, att_src, att_dst, Wedge, att_edge, bias_c, Wout, bout,
        vs, va, vb, we, cb);
    // K1: one wave per node (dominant: 76.8 MB of x)
    k1_node<<<(N * 64 + 255) / 256, 256, 0, stream>>>(
        x, vs, va, vb, s, asrc, adst, deg, aesum, denom, num, N);
    // K2: one thread per edge, all edge-side math + atomics
    k2_edge<<<(E + 255) / 256, 256, 0, stream>>>(
        ea, src, dst, we, asrc, adst, s, deg, aesum, denom, num, E);
    // K3: per-node epilogue
    k3_out<<<(N + 255) / 256, 256, 0, stream>>>(
        asrc, adst, deg, aesum, denom, num, s, cb, out, N);
}